// Round 9
// baseline (371.549 us; speedup 1.0000x reference)
//
#include <hip/hip_runtime.h>
#include <stdint.h>

// LeNet5-XNOR fused pipeline, round 9.
// vs round 8:
//  - conv1_mfma: persistent-ZERO C operand (no per-py acc zero-inits),
//    pairwise u32 limb unpack (3 ops per 2 taps), per-lane byte offsets
//    folded once so per-py reads use the ds imm offset.
//  - conv2lin: hsh LDS round-trip deleted (same-lane indices; hv registers).
//    LDS 23.5 -> 15.4 KB.
//  - sumT: 256 blocks x 32 images.

#define NIMG 8192

typedef __attribute__((ext_vector_type(8))) _Float16 f16x8;
typedef __attribute__((ext_vector_type(16))) float f32x16;

// ---------------- workspace layout ----------------
// 0       : 20 f32     mean
// 128     : 1250 u32   wp2
// 5632    : 500 f32    alpha
// 7680    : 500*20 u64 lwp
// 87808   : 256*1024 f32 partial image sums
// 1136384 : 8192*196 u32 b1p

__global__ __launch_bounds__(64) void prep_k(const float* __restrict__ lw,
                                             const float* __restrict__ w2,
                                             unsigned long long* __restrict__ lwp,
                                             float* __restrict__ alpha,
                                             uint32_t* __restrict__ wp2) {
  int b = blockIdx.x, t = threadIdx.x;
  if (b < 500) {
    int j = b;
    float pa = 0.f;
    for (int k = t; k < 1250; k += 64) pa += fabsf(lw[j * 1250 + k]);
    for (int o = 32; o > 0; o >>= 1) pa += __shfl_down(pa, o, 64);
    if (t == 0) alpha[j] = pa / 1250.0f;
    if (t < 20) {
      unsigned long long m = 0;
      int base = j * 1250 + t * 64;
      int lim = 1250 - t * 64; if (lim > 64) lim = 64;
      for (int bb = 0; bb < lim; ++bb)
        if (lw[base + bb] > 0.f) m |= (1ull << bb);
      lwp[j * 20 + t] = m;
    }
  } else {
    int idx = (b - 500) * 64 + t;
    if (idx < 1250) {
      int oc = idx / 25, k = idx % 25;
      uint32_t m = 0;
      for (int ic = 0; ic < 20; ++ic)
        if (w2[(oc * 20 + ic) * 25 + k] > 0.f) m |= (1u << ic);
      wp2[idx] = m;
    }
  }
}

__global__ __launch_bounds__(256) void sumT_k(const float* __restrict__ x,
                                              float* __restrict__ partial) {
  int b = blockIdx.x, t = threadIdx.x;
  const float4* xv = (const float4*)x + (size_t)b * 32 * 256;
  float ax = 0.f, ay = 0.f, az = 0.f, aw = 0.f;
  for (int nn = 0; nn < 32; ++nn) {
    float4 v = xv[nn * 256 + t];
    ax += v.x; ay += v.y; az += v.z; aw += v.w;
  }
  float4 r; r.x = ax; r.y = ay; r.z = az; r.w = aw;
  ((float4*)(partial + (size_t)b * 1024))[t] = r;
}

__global__ __launch_bounds__(256) void mean_k(const float* __restrict__ partial,
                                              const float* __restrict__ w1,
                                              float* __restrict__ mean) {
  __shared__ float Tsh[1024];
  __shared__ double U8[25][8];
  __shared__ double U[25];
  int t = threadIdx.x;
  for (int e = t; e < 1024; e += 256) {
    double s = 0.0;
    for (int b = 0; b < 256; ++b) s += (double)partial[b * 1024 + e];
    Tsh[e] = (float)s;
  }
  __syncthreads();
  if (t < 200) {
    int tap = t >> 3, part = t & 7;
    int ky = tap / 5, kx = tap % 5;
    double s = 0.0;
    for (int p = part * 98; p < part * 98 + 98; ++p) {
      int py = p / 28, px = p % 28;
      s += (double)Tsh[(py + ky) * 32 + px + kx];
    }
    U8[tap][part] = s;
  }
  __syncthreads();
  if (t < 25) {
    double s = 0.0;
    for (int i = 0; i < 8; ++i) s += U8[t][i];
    U[t] = s;
  }
  __syncthreads();
  if (t < 20) {
    double s = 0.0;
    for (int q = 0; q < 25; ++q) s += (double)w1[t * 25 + q] * U[q];
    mean[t] = (float)(s / (8192.0 * 784.0));
  }
}

__device__ inline uint32_t pack_f16_pair(float fv) {
  _Float16 h = (_Float16)fv;
  float rem = fv - (float)h;
  _Float16 l = (_Float16)(rem * 4096.0f);
  uint32_t hb = (uint32_t)__builtin_bit_cast(unsigned short, h);
  uint32_t lb = (uint32_t)__builtin_bit_cast(unsigned short, l);
  return (hb << 16) | lb;
}

// conv1 via MFMA (fp16 2-limb split). One wave per image; block = 4 images.
__global__ __launch_bounds__(256) void conv1_mfma_k(const float* __restrict__ x,
                                                    const float* __restrict__ w1,
                                                    const float* __restrict__ mean,
                                                    uint32_t* __restrict__ b1p) {
  __shared__ uint32_t ximg[4][1032];  // (f16_hi<<16)|f16_lo(x4096)
  int tid = threadIdx.x;
  int wave = tid >> 6, lane = tid & 63;
  int n = blockIdx.x * 4 + wave;
  uint32_t* xs = ximg[wave];

  // ---- stage image as fp16 limb pairs ----
  const float4* xin = (const float4*)(x + (size_t)n * 1024);
#pragma unroll
  for (int i = 0; i < 4; ++i) {
    float4 v = xin[i * 64 + lane];
    float fv[4] = {v.x, v.y, v.z, v.w};
#pragma unroll
    for (int e = 0; e < 4; ++e)
      xs[4 * (i * 64 + lane) + e] = pack_f16_pair(fv[e]);
  }

  // ---- B fragments (weights hi/lo, 2 K-halves) ----
  int bc = lane & 31;          // channel (N dim)
  int khsel = lane >> 5;       // 8-k group
  f16x8 Bh[2], Bl[2];
#pragma unroll
  for (int kh = 0; kh < 2; ++kh)
#pragma unroll
    for (int j = 0; j < 8; ++j) {
      int t = kh * 16 + khsel * 8 + j;
      float wv = (bc < 20 && t < 25) ? w1[bc * 25 + t] : 0.f;
      uint32_t pp = pack_f16_pair(wv);
      Bh[kh][j] = __builtin_bit_cast(_Float16, (unsigned short)(pp >> 16));
      Bl[kh][j] = __builtin_bit_cast(_Float16, (unsigned short)(pp & 0xffffu));
    }
  float mv = (bc < 20) ? mean[bc] : 3.0e38f;

  int m = lane & 31;  // output px (M dim); 28..31 garbage

  // ---- per-lane element offsets (m folded in once); per-py adds become imm ----
  int aoff[2][8];
#pragma unroll
  for (int kh = 0; kh < 2; ++kh)
#pragma unroll
    for (int j = 0; j < 8; ++j) {
      int t = kh * 16 + khsel * 8 + j;
      if (t > 24) t = 24;  // pad taps multiply zero weights
      aoff[kh][j] = m + (t / 5) * 32 + (t % 5);
    }

  const float INV = 1.0f / 4096.0f;
  f32x16 ZERO;
#pragma unroll
  for (int i = 0; i < 16; ++i) ZERO[i] = 0.f;

  for (int pp = 0; pp < 14; ++pp) {
    unsigned long long bacc[16];
#pragma unroll
    for (int r = 0; r < 16; ++r) bacc[r] = 0ull;
#pragma unroll
    for (int py2 = 0; py2 < 2; ++py2) {
      int pybase = (2 * pp + py2) * 32;
      uint32_t raw[16];
#pragma unroll
      for (int kh = 0; kh < 2; ++kh)
#pragma unroll
        for (int j = 0; j < 8; ++j)
          raw[kh * 8 + j] = xs[pybase + aoff[kh][j]];
      // pairwise limb unpack: word jj of frag kh = taps (2jj, 2jj+1)
      f16x8 Ah[2], Al[2];
#pragma unroll
      for (int kh = 0; kh < 2; ++kh) {
        uint32_t hw[4], lw2[4];
#pragma unroll
        for (int jj = 0; jj < 4; ++jj) {
          uint32_t v0 = raw[kh * 8 + 2 * jj], v1 = raw[kh * 8 + 2 * jj + 1];
          hw[jj] = (v1 & 0xFFFF0000u) | (v0 >> 16);
          lw2[jj] = (v1 << 16) | (v0 & 0xFFFFu);
        }
        struct U4 { uint32_t a, b, c, d; };
        U4 hv4 = {hw[0], hw[1], hw[2], hw[3]};
        U4 lv4 = {lw2[0], lw2[1], lw2[2], lw2[3]};
        Ah[kh] = __builtin_bit_cast(f16x8, hv4);
        Al[kh] = __builtin_bit_cast(f16x8, lv4);
      }
      f32x16 acc0, acc1;
      acc0 = __builtin_amdgcn_mfma_f32_32x32x16_f16(Ah[0], Bh[0], ZERO, 0, 0, 0);
      acc0 = __builtin_amdgcn_mfma_f32_32x32x16_f16(Ah[1], Bh[1], acc0, 0, 0, 0);
      acc1 = __builtin_amdgcn_mfma_f32_32x32x16_f16(Ah[0], Bl[0], ZERO, 0, 0, 0);
      acc1 = __builtin_amdgcn_mfma_f32_32x32x16_f16(Ah[1], Bl[1], acc1, 0, 0, 0);
      acc1 = __builtin_amdgcn_mfma_f32_32x32x16_f16(Al[0], Bh[0], acc1, 0, 0, 0);
      acc1 = __builtin_amdgcn_mfma_f32_32x32x16_f16(Al[1], Bh[1], acc1, 0, 0, 0);
      // C/D: channel = lane&31, px = (r&3) + 8*(r>>2) + 4*(lane>>5)
#pragma unroll
      for (int r = 0; r < 16; ++r)
        bacc[r] |= __ballot(fmaf(INV, acc1[r], acc0[r]) > mv);
    }
    uint32_t pm = 0;
#pragma unroll
    for (int pc = 0; pc < 14; ++pc) {
      int px0 = 2 * pc;
      int r0 = (px0 & 3) + 4 * (px0 >> 3);
      int h0 = (px0 >> 2) & 1;
      unsigned long long mm = bacc[r0] | bacc[r0 + 1];
      uint32_t val = (uint32_t)(mm >> (32 * h0));
      if (lane == pc) pm = val;
    }
    if (lane < 14) b1p[(size_t)n * 196 + pp * 14 + lane] = pm;
  }
}

// Fused conv2+pool/sign+linear+fc. Block = 4 images, one wave per image.
__global__ __launch_bounds__(256) void conv2lin_k(const uint32_t* __restrict__ b1p,
                                                  const uint32_t* __restrict__ wp2,
                                                  const unsigned long long* __restrict__ lwp,
                                                  const float* __restrict__ alpha,
                                                  const float* __restrict__ fcw,
                                                  const float* __restrict__ fcb,
                                                  float* __restrict__ out) {
  __shared__ uint32_t wsh[1250];
  __shared__ uint32_t bm[4][196];
  __shared__ int sumpc[4][100];
  __shared__ signed char s2sh[4][1280];
  int tid = threadIdx.x;
  int wave = tid >> 6, lane = tid & 63;
  int n = blockIdx.x * 4 + wave;

  for (int i = tid; i < 1250; i += 256) wsh[i] = wp2[i];
#pragma unroll
  for (int rd = 0; rd < 4; ++rd) {
    int idx = rd * 64 + lane;
    if (idx < 196) bm[wave][idx] = b1p[(size_t)n * 196 + idx];
  }
  __syncthreads();

#pragma unroll
  for (int rd = 0; rd < 2; ++rd) {
    int pp = rd * 64 + lane;
    if (pp < 100) {
      int Y = pp / 10, X = pp % 10, s = 0;
#pragma unroll
      for (int ky = 0; ky < 5; ++ky)
#pragma unroll
        for (int kx = 0; kx < 5; ++kx)
          s += __popc(bm[wave][(Y + ky) * 14 + X + kx]);
      sumpc[wave][pp] = s;
    }
  }

#pragma unroll
  for (int rd = 0; rd < 4; ++rd) {
    int unit = rd * 64 + lane;
    if (unit < 250) {
      int oc = unit / 5, r = unit % 5;
      uint32_t w[25];
#pragma unroll
      for (int i = 0; i < 25; ++i) w[i] = wsh[oc * 25 + i];
      for (int pc = 0; pc < 5; ++pc) {
        uint32_t pa[6][6];
#pragma unroll
        for (int rr = 0; rr < 6; ++rr)
#pragma unroll
          for (int cc = 0; cc < 6; ++cc)
            pa[rr][cc] = bm[wave][(2 * r + rr) * 14 + 2 * pc + cc];
        int best = -1000000;
#pragma unroll
        for (int dy = 0; dy < 2; ++dy)
#pragma unroll
          for (int dx = 0; dx < 2; ++dx) {
            int a = 0;
#pragma unroll
            for (int ky = 0; ky < 5; ++ky)
#pragma unroll
              for (int kx = 0; kx < 5; ++kx)
                a += __popc(w[ky * 5 + kx] & pa[dy + ky][dx + kx]);
            a = 2 * a - sumpc[wave][(2 * r + dy) * 10 + 2 * pc + dx];
            if (a > best) best = a;
          }
        s2sh[wave][5 * unit + pc] = (signed char)((best > 0) - (best < 0));
      }
    }
  }
  if (lane < 30) s2sh[wave][1250 + lane] = 0;

  unsigned long long Pm[20], Nm[20];
  int cp = 0, cn = 0;
#pragma unroll
  for (int k = 0; k < 20; ++k) {
    signed char v = s2sh[wave][k * 64 + lane];
    unsigned long long P = __ballot(v > 0);
    unsigned long long N = __ballot(v < 0);
    Pm[k] = P; Nm[k] = N;
    cp += __popcll(P); cn += __popcll(N);
  }

  // binary linear 1250->500 + clip; h stays in registers (same lane indices
  // as the fc phase below — no LDS round-trip needed)
  float hv[8];
#pragma unroll
  for (int rd = 0; rd < 8; ++rd) {
    int j = rd * 64 + lane;
    float y = 0.f;
    if (j < 500) {
      const ulonglong2* W2 = (const ulonglong2*)(lwp + (size_t)j * 20);
      int a = 0, b = 0;
#pragma unroll
      for (int i = 0; i < 10; ++i) {
        ulonglong2 w2v = W2[i];
        a += __popcll(w2v.x & Pm[2 * i]) + __popcll(w2v.y & Pm[2 * i + 1]);
        b += __popcll(w2v.x & Nm[2 * i]) + __popcll(w2v.y & Nm[2 * i + 1]);
      }
      int dot = 2 * (a - b) - cp + cn;
      y = alpha[j] * (float)dot;
      y = fminf(1.0f, fmaxf(-1.0f, y));
    }
    hv[rd] = y;
  }

  // fc 500->10, wave shuffle reduce (hv=0 for j>=500 keeps sums exact)
#pragma unroll
  for (int o = 0; o < 10; ++o) {
    float pa = 0.f;
#pragma unroll
    for (int k = 0; k < 8; ++k) {
      int j = k * 64 + lane;
      if (j < 500) pa += hv[k] * fcw[o * 500 + j];
    }
    for (int off = 32; off > 0; off >>= 1) pa += __shfl_down(pa, off, 64);
    if (lane == 0) out[(size_t)n * 10 + o] = pa + fcb[o];
  }
}

extern "C" void kernel_launch(void* const* d_in, const int* in_sizes, int n_in,
                              void* d_out, int out_size, void* d_ws, size_t ws_size,
                              hipStream_t stream) {
  const float* x   = (const float*)d_in[0];
  const float* w1  = (const float*)d_in[1];
  const float* w2  = (const float*)d_in[2];
  const float* lw  = (const float*)d_in[3];
  const float* fcw = (const float*)d_in[4];
  const float* fcb = (const float*)d_in[5];
  float* out = (float*)d_out;
  char* ws = (char*)d_ws;

  float*    mean  = (float*)(ws + 0);
  uint32_t* wp2   = (uint32_t*)(ws + 128);
  float*    alpha = (float*)(ws + 5632);
  unsigned long long* lwp = (unsigned long long*)(ws + 7680);
  float*    partial = (float*)(ws + 87808);
  uint32_t* b1p   = (uint32_t*)(ws + 1136384);

  prep_k<<<520, 64, 0, stream>>>(lw, w2, lwp, alpha, wp2);
  sumT_k<<<256, 256, 0, stream>>>(x, partial);
  mean_k<<<1, 256, 0, stream>>>(partial, w1, mean);
  conv1_mfma_k<<<2048, 256, 0, stream>>>(x, w1, mean, b1p);
  conv2lin_k<<<2048, 256, 0, stream>>>(b1p, wp2, lwp, alpha, fcw, fcb, out);
}

// Round 10
// 270.198 us; speedup vs baseline: 1.3751x; 1.3751x over previous
//
#include <hip/hip_runtime.h>
#include <stdint.h>

// LeNet5-XNOR fused pipeline, round 10.
// vs round 9 (which regressed; both changes reverted):
//  - conv1_mfma: round-8 version VERBATIM (known ~105us).
//  - conv2lin: round-4 per-wave code, but 8 images/block (512 thr, 8 waves).
//    s2sh/hsh share one wave-local union region -> 30.1KB LDS -> 4 blocks/CU
//    x 8 waves = full 32-wave occupancy; wsh staging amortized 2x.
//    (r9 lesson: keep the hsh LDS round-trip — it fences register lifetimes.)
//  - prep + sumT merged into one 386-block dispatch.

#define NIMG 8192

typedef __attribute__((ext_vector_type(8))) _Float16 f16x8;
typedef __attribute__((ext_vector_type(16))) float f32x16;

// ---------------- workspace layout ----------------
// 0       : 20 f32     mean
// 128     : 1250 u32   wp2
// 5632    : 500 f32    alpha
// 7680    : 500*20 u64 lwp
// 87808   : 256*1024 f32 partial image sums
// 1136384 : 8192*196 u32 b1p

// blocks 0..124: prep_lin (4 j per block, 1 j per wave)
// blocks 125..129: wp2 pack
// blocks 130..385: sumT partials (32 images each)
__global__ __launch_bounds__(256) void prepsum_k(const float* __restrict__ lw,
                                                 const float* __restrict__ w2,
                                                 const float* __restrict__ x,
                                                 unsigned long long* __restrict__ lwp,
                                                 float* __restrict__ alpha,
                                                 uint32_t* __restrict__ wp2,
                                                 float* __restrict__ partial) {
  int b = blockIdx.x, tid = threadIdx.x;
  if (b < 125) {
    int wave = tid >> 6, lane = tid & 63;
    int j = b * 4 + wave;
    float pa = 0.f;
    for (int k = lane; k < 1250; k += 64) pa += fabsf(lw[j * 1250 + k]);
    for (int o = 32; o > 0; o >>= 1) pa += __shfl_down(pa, o, 64);
    if (lane == 0) alpha[j] = pa / 1250.0f;
    if (lane < 20) {
      unsigned long long m = 0;
      int base = j * 1250 + lane * 64;
      int lim = 1250 - lane * 64; if (lim > 64) lim = 64;
      for (int bb = 0; bb < lim; ++bb)
        if (lw[base + bb] > 0.f) m |= (1ull << bb);
      lwp[j * 20 + lane] = m;
    }
  } else if (b < 130) {
    int idx = (b - 125) * 256 + tid;
    if (idx < 1250) {
      int oc = idx / 25, k = idx % 25;
      uint32_t m = 0;
      for (int ic = 0; ic < 20; ++ic)
        if (w2[(oc * 20 + ic) * 25 + k] > 0.f) m |= (1u << ic);
      wp2[idx] = m;
    }
  } else {
    int sb = b - 130;
    const float4* xv = (const float4*)x + (size_t)sb * 32 * 256;
    float ax = 0.f, ay = 0.f, az = 0.f, aw = 0.f;
    for (int nn = 0; nn < 32; ++nn) {
      float4 v = xv[nn * 256 + tid];
      ax += v.x; ay += v.y; az += v.z; aw += v.w;
    }
    float4 r; r.x = ax; r.y = ay; r.z = az; r.w = aw;
    ((float4*)(partial + (size_t)sb * 1024))[tid] = r;
  }
}

__global__ __launch_bounds__(256) void mean_k(const float* __restrict__ partial,
                                              const float* __restrict__ w1,
                                              float* __restrict__ mean) {
  __shared__ float Tsh[1024];
  __shared__ double U8[25][8];
  __shared__ double U[25];
  int t = threadIdx.x;
  for (int e = t; e < 1024; e += 256) {
    double s = 0.0;
    for (int b = 0; b < 256; ++b) s += (double)partial[b * 1024 + e];
    Tsh[e] = (float)s;
  }
  __syncthreads();
  if (t < 200) {
    int tap = t >> 3, part = t & 7;
    int ky = tap / 5, kx = tap % 5;
    double s = 0.0;
    for (int p = part * 98; p < part * 98 + 98; ++p) {
      int py = p / 28, px = p % 28;
      s += (double)Tsh[(py + ky) * 32 + px + kx];
    }
    U8[tap][part] = s;
  }
  __syncthreads();
  if (t < 25) {
    double s = 0.0;
    for (int i = 0; i < 8; ++i) s += U8[t][i];
    U[t] = s;
  }
  __syncthreads();
  if (t < 20) {
    double s = 0.0;
    for (int q = 0; q < 25; ++q) s += (double)w1[t * 25 + q] * U[q];
    mean[t] = (float)(s / (8192.0 * 784.0));
  }
}

__device__ inline uint32_t pack_f16_pair(float fv) {
  _Float16 h = (_Float16)fv;
  float rem = fv - (float)h;
  _Float16 l = (_Float16)(rem * 4096.0f);
  uint32_t hb = (uint32_t)__builtin_bit_cast(unsigned short, h);
  uint32_t lb = (uint32_t)__builtin_bit_cast(unsigned short, l);
  return (hb << 16) | lb;
}

// conv1 via MFMA (fp16 2-limb split). Round-8 version verbatim.
__global__ __launch_bounds__(256) void conv1_mfma_k(const float* __restrict__ x,
                                                    const float* __restrict__ w1,
                                                    const float* __restrict__ mean,
                                                    uint32_t* __restrict__ b1p) {
  __shared__ uint32_t ximg[4][1032];
  int tid = threadIdx.x;
  int wave = tid >> 6, lane = tid & 63;
  int n = blockIdx.x * 4 + wave;
  uint32_t* xs = ximg[wave];

  const float4* xin = (const float4*)(x + (size_t)n * 1024);
#pragma unroll
  for (int i = 0; i < 4; ++i) {
    float4 v = xin[i * 64 + lane];
    float fv[4] = {v.x, v.y, v.z, v.w};
#pragma unroll
    for (int e = 0; e < 4; ++e)
      xs[4 * (i * 64 + lane) + e] = pack_f16_pair(fv[e]);
  }

  int bc = lane & 31;
  int khsel = lane >> 5;
  f16x8 Bh[2], Bl[2];
#pragma unroll
  for (int kh = 0; kh < 2; ++kh)
#pragma unroll
    for (int j = 0; j < 8; ++j) {
      int t = kh * 16 + khsel * 8 + j;
      float wv = (bc < 20 && t < 25) ? w1[bc * 25 + t] : 0.f;
      uint32_t pp = pack_f16_pair(wv);
      Bh[kh][j] = __builtin_bit_cast(_Float16, (unsigned short)(pp >> 16));
      Bl[kh][j] = __builtin_bit_cast(_Float16, (unsigned short)(pp & 0xffffu));
    }
  float mv = (bc < 20) ? mean[bc] : 3.0e38f;

  int offs[2][8];
#pragma unroll
  for (int kh = 0; kh < 2; ++kh)
#pragma unroll
    for (int j = 0; j < 8; ++j) {
      int t = kh * 16 + khsel * 8 + j;
      if (t > 24) t = 24;
      offs[kh][j] = (t / 5) * 32 + (t % 5);
    }

  int m = lane & 31;
  const float INV = 1.0f / 4096.0f;

  for (int pp = 0; pp < 14; ++pp) {
    unsigned long long bacc[16];
#pragma unroll
    for (int r = 0; r < 16; ++r) bacc[r] = 0ull;
#pragma unroll
    for (int py2 = 0; py2 < 2; ++py2) {
      int py = 2 * pp + py2;
      int base = py * 32 + m;
      f16x8 Ah[2], Al[2];
#pragma unroll
      for (int kh = 0; kh < 2; ++kh)
#pragma unroll
        for (int j = 0; j < 8; ++j) {
          uint32_t v = xs[base + offs[kh][j]];
          Ah[kh][j] = __builtin_bit_cast(_Float16, (unsigned short)(v >> 16));
          Al[kh][j] = __builtin_bit_cast(_Float16, (unsigned short)(v & 0xffffu));
        }
      f32x16 acc0, acc1;
#pragma unroll
      for (int i = 0; i < 16; ++i) { acc0[i] = 0.f; acc1[i] = 0.f; }
      acc0 = __builtin_amdgcn_mfma_f32_32x32x16_f16(Ah[0], Bh[0], acc0, 0, 0, 0);
      acc0 = __builtin_amdgcn_mfma_f32_32x32x16_f16(Ah[1], Bh[1], acc0, 0, 0, 0);
      acc1 = __builtin_amdgcn_mfma_f32_32x32x16_f16(Ah[0], Bl[0], acc1, 0, 0, 0);
      acc1 = __builtin_amdgcn_mfma_f32_32x32x16_f16(Ah[1], Bl[1], acc1, 0, 0, 0);
      acc1 = __builtin_amdgcn_mfma_f32_32x32x16_f16(Al[0], Bh[0], acc1, 0, 0, 0);
      acc1 = __builtin_amdgcn_mfma_f32_32x32x16_f16(Al[1], Bh[1], acc1, 0, 0, 0);
#pragma unroll
      for (int r = 0; r < 16; ++r)
        bacc[r] |= __ballot((acc0[r] + INV * acc1[r]) > mv);
    }
    uint32_t pm = 0;
#pragma unroll
    for (int pc = 0; pc < 14; ++pc) {
      int px0 = 2 * pc;
      int r0 = (px0 & 3) + 4 * (px0 >> 3);
      int h0 = (px0 >> 2) & 1;
      unsigned long long mm = bacc[r0] | bacc[r0 + 1];
      uint32_t val = (uint32_t)(mm >> (32 * h0));
      if (lane == pc) pm = val;
    }
    if (lane < 14) b1p[(size_t)n * 196 + pp * 14 + lane] = pm;
  }
}

// Fused conv2+pool/sign+linear+fc. Block = 8 images, one wave per image.
// Per-wave code identical to round 4; s2sh/hsh overlaid (wave-local,
// sequential lifetimes) to keep LDS at 30.1KB -> 4 blocks/CU, 32 waves.
__global__ __launch_bounds__(512) void conv2lin_k(const uint32_t* __restrict__ b1p,
                                                  const uint32_t* __restrict__ wp2,
                                                  const unsigned long long* __restrict__ lwp,
                                                  const float* __restrict__ alpha,
                                                  const float* __restrict__ fcw,
                                                  const float* __restrict__ fcb,
                                                  float* __restrict__ out) {
  __shared__ uint32_t wsh[1250];
  __shared__ uint32_t bm[8][196];
  __shared__ int sumpc[8][100];
  __shared__ char uni[8][2048];  // s2 signs (1280B) then hsh floats (2048B)
  int tid = threadIdx.x;
  int wave = tid >> 6, lane = tid & 63;
  int n = blockIdx.x * 8 + wave;
  signed char* s2w = (signed char*)uni[wave];
  float* hshw = (float*)uni[wave];

  for (int i = tid; i < 1250; i += 512) wsh[i] = wp2[i];
#pragma unroll
  for (int rd = 0; rd < 4; ++rd) {
    int idx = rd * 64 + lane;
    if (idx < 196) bm[wave][idx] = b1p[(size_t)n * 196 + idx];
  }
  __syncthreads();

#pragma unroll
  for (int rd = 0; rd < 2; ++rd) {
    int pp = rd * 64 + lane;
    if (pp < 100) {
      int Y = pp / 10, X = pp % 10, s = 0;
#pragma unroll
      for (int ky = 0; ky < 5; ++ky)
#pragma unroll
        for (int kx = 0; kx < 5; ++kx)
          s += __popc(bm[wave][(Y + ky) * 14 + X + kx]);
      sumpc[wave][pp] = s;
    }
  }

#pragma unroll
  for (int rd = 0; rd < 4; ++rd) {
    int unit = rd * 64 + lane;
    if (unit < 250) {
      int oc = unit / 5, r = unit % 5;
      uint32_t w[25];
#pragma unroll
      for (int i = 0; i < 25; ++i) w[i] = wsh[oc * 25 + i];
      for (int pc = 0; pc < 5; ++pc) {
        uint32_t pa[6][6];
#pragma unroll
        for (int rr = 0; rr < 6; ++rr)
#pragma unroll
          for (int cc = 0; cc < 6; ++cc)
            pa[rr][cc] = bm[wave][(2 * r + rr) * 14 + 2 * pc + cc];
        int best = -1000000;
#pragma unroll
        for (int dy = 0; dy < 2; ++dy)
#pragma unroll
          for (int dx = 0; dx < 2; ++dx) {
            int a = 0;
#pragma unroll
            for (int ky = 0; ky < 5; ++ky)
#pragma unroll
              for (int kx = 0; kx < 5; ++kx)
                a += __popc(w[ky * 5 + kx] & pa[dy + ky][dx + kx]);
            a = 2 * a - sumpc[wave][(2 * r + dy) * 10 + 2 * pc + dx];
            if (a > best) best = a;
          }
        s2w[5 * unit + pc] = (signed char)((best > 0) - (best < 0));
      }
    }
  }
  if (lane < 30) s2w[1250 + lane] = 0;

  unsigned long long Pm[20], Nm[20];
  int cp = 0, cn = 0;
#pragma unroll
  for (int k = 0; k < 20; ++k) {
    signed char v = s2w[k * 64 + lane];
    unsigned long long P = __ballot(v > 0);
    unsigned long long N = __ballot(v < 0);
    Pm[k] = P; Nm[k] = N;
    cp += __popcll(P); cn += __popcll(N);
  }
  // s2w fully consumed (wave-local); region now reused as hshw floats.

#pragma unroll
  for (int rd = 0; rd < 8; ++rd) {
    int j = rd * 64 + lane;
    float y = 0.f;
    if (j < 500) {
      const ulonglong2* W2 = (const ulonglong2*)(lwp + (size_t)j * 20);
      int a = 0, b = 0;
#pragma unroll
      for (int i = 0; i < 10; ++i) {
        ulonglong2 w2v = W2[i];
        a += __popcll(w2v.x & Pm[2 * i]) + __popcll(w2v.y & Pm[2 * i + 1]);
        b += __popcll(w2v.x & Nm[2 * i]) + __popcll(w2v.y & Nm[2 * i + 1]);
      }
      int dot = 2 * (a - b) - cp + cn;
      y = alpha[j] * (float)dot;
      y = fminf(1.0f, fmaxf(-1.0f, y));
    }
    hshw[rd * 64 + lane] = y;
  }

  float hv[8];
#pragma unroll
  for (int k = 0; k < 8; ++k) hv[k] = hshw[k * 64 + lane];
#pragma unroll
  for (int o = 0; o < 10; ++o) {
    float pa = 0.f;
#pragma unroll
    for (int k = 0; k < 8; ++k) {
      int j = k * 64 + lane;
      if (j < 500) pa += hv[k] * fcw[o * 500 + j];
    }
    for (int off = 32; off > 0; off >>= 1) pa += __shfl_down(pa, off, 64);
    if (lane == 0) out[(size_t)n * 10 + o] = pa + fcb[o];
  }
}

extern "C" void kernel_launch(void* const* d_in, const int* in_sizes, int n_in,
                              void* d_out, int out_size, void* d_ws, size_t ws_size,
                              hipStream_t stream) {
  const float* x   = (const float*)d_in[0];
  const float* w1  = (const float*)d_in[1];
  const float* w2  = (const float*)d_in[2];
  const float* lw  = (const float*)d_in[3];
  const float* fcw = (const float*)d_in[4];
  const float* fcb = (const float*)d_in[5];
  float* out = (float*)d_out;
  char* ws = (char*)d_ws;

  float*    mean  = (float*)(ws + 0);
  uint32_t* wp2   = (uint32_t*)(ws + 128);
  float*    alpha = (float*)(ws + 5632);
  unsigned long long* lwp = (unsigned long long*)(ws + 7680);
  float*    partial = (float*)(ws + 87808);
  uint32_t* b1p   = (uint32_t*)(ws + 1136384);

  prepsum_k<<<386, 256, 0, stream>>>(lw, w2, x, lwp, alpha, wp2, partial);
  mean_k<<<1, 256, 0, stream>>>(partial, w1, mean);
  conv1_mfma_k<<<2048, 256, 0, stream>>>(x, w1, mean, b1p);
  conv2lin_k<<<1024, 512, 0, stream>>>(b1p, wp2, lwp, alpha, fcw, fcb, out);
}

// Round 11
// 245.475 us; speedup vs baseline: 1.5136x; 1.1007x over previous
//
#include <hip/hip_runtime.h>
#include <stdint.h>

// LeNet5-XNOR fused pipeline, round 11.
// vs round 10 (conv1/conv2lin byte-identical — both known-good):
//  - The mean path was a serial chokepoint: single-block mean_k did 262K
//    global loads on ONE CU (~40us) while the whole GPU waited (conv1 depends
//    on mean). New reduce_k (32 blocks) collapses 256 partials -> 8; mean_k's
//    serial section is now ~8K loads (~2-3us).

#define NIMG 8192

typedef __attribute__((ext_vector_type(8))) _Float16 f16x8;
typedef __attribute__((ext_vector_type(16))) float f32x16;

// ---------------- workspace layout ----------------
// 0       : 20 f32     mean
// 128     : 1250 u32   wp2
// 5632    : 500 f32    alpha
// 7680    : 500*20 u64 lwp
// 87808   : 256*1024 f32 partial image sums
// 1136384 : 8192*196 u32 b1p   (ends 7558912)
// 7558912 : 8*1024 f32 partial2

// blocks 0..124: prep_lin; 125..129: wp2 pack; 130..385: sumT partials
__global__ __launch_bounds__(256) void prepsum_k(const float* __restrict__ lw,
                                                 const float* __restrict__ w2,
                                                 const float* __restrict__ x,
                                                 unsigned long long* __restrict__ lwp,
                                                 float* __restrict__ alpha,
                                                 uint32_t* __restrict__ wp2,
                                                 float* __restrict__ partial) {
  int b = blockIdx.x, tid = threadIdx.x;
  if (b < 125) {
    int wave = tid >> 6, lane = tid & 63;
    int j = b * 4 + wave;
    float pa = 0.f;
    for (int k = lane; k < 1250; k += 64) pa += fabsf(lw[j * 1250 + k]);
    for (int o = 32; o > 0; o >>= 1) pa += __shfl_down(pa, o, 64);
    if (lane == 0) alpha[j] = pa / 1250.0f;
    if (lane < 20) {
      unsigned long long m = 0;
      int base = j * 1250 + lane * 64;
      int lim = 1250 - lane * 64; if (lim > 64) lim = 64;
      for (int bb = 0; bb < lim; ++bb)
        if (lw[base + bb] > 0.f) m |= (1ull << bb);
      lwp[j * 20 + lane] = m;
    }
  } else if (b < 130) {
    int idx = (b - 125) * 256 + tid;
    if (idx < 1250) {
      int oc = idx / 25, k = idx % 25;
      uint32_t m = 0;
      for (int ic = 0; ic < 20; ++ic)
        if (w2[(oc * 20 + ic) * 25 + k] > 0.f) m |= (1u << ic);
      wp2[idx] = m;
    }
  } else {
    int sb = b - 130;
    const float4* xv = (const float4*)x + (size_t)sb * 32 * 256;
    float ax = 0.f, ay = 0.f, az = 0.f, aw = 0.f;
    for (int nn = 0; nn < 32; ++nn) {
      float4 v = xv[nn * 256 + tid];
      ax += v.x; ay += v.y; az += v.z; aw += v.w;
    }
    float4 r; r.x = ax; r.y = ay; r.z = az; r.w = aw;
    ((float4*)(partial + (size_t)sb * 1024))[tid] = r;
  }
}

// 256 partials -> 8. block b: element group b&3 (256 elems), partial group
// b>>2 (32 partials).
__global__ __launch_bounds__(256) void reduce_k(const float* __restrict__ partial,
                                                float* __restrict__ partial2) {
  int b = blockIdx.x, tid = threadIdx.x;
  int e = (b & 3) * 256 + tid;
  int p0 = (b >> 2) * 32;
  float s = 0.f;
#pragma unroll
  for (int p = 0; p < 32; ++p) s += partial[(size_t)(p0 + p) * 1024 + e];
  partial2[(size_t)(b >> 2) * 1024 + e] = s;
}

__global__ __launch_bounds__(256) void mean_k(const float* __restrict__ partial2,
                                              const float* __restrict__ w1,
                                              float* __restrict__ mean) {
  __shared__ float Tsh[1024];
  __shared__ double U8[25][8];
  __shared__ double U[25];
  int t = threadIdx.x;
  for (int e = t; e < 1024; e += 256) {
    double s = 0.0;
#pragma unroll
    for (int b = 0; b < 8; ++b) s += (double)partial2[b * 1024 + e];
    Tsh[e] = (float)s;
  }
  __syncthreads();
  if (t < 200) {
    int tap = t >> 3, part = t & 7;
    int ky = tap / 5, kx = tap % 5;
    double s = 0.0;
    for (int p = part * 98; p < part * 98 + 98; ++p) {
      int py = p / 28, px = p % 28;
      s += (double)Tsh[(py + ky) * 32 + px + kx];
    }
    U8[tap][part] = s;
  }
  __syncthreads();
  if (t < 25) {
    double s = 0.0;
    for (int i = 0; i < 8; ++i) s += U8[t][i];
    U[t] = s;
  }
  __syncthreads();
  if (t < 20) {
    double s = 0.0;
    for (int q = 0; q < 25; ++q) s += (double)w1[t * 25 + q] * U[q];
    mean[t] = (float)(s / (8192.0 * 784.0));
  }
}

__device__ inline uint32_t pack_f16_pair(float fv) {
  _Float16 h = (_Float16)fv;
  float rem = fv - (float)h;
  _Float16 l = (_Float16)(rem * 4096.0f);
  uint32_t hb = (uint32_t)__builtin_bit_cast(unsigned short, h);
  uint32_t lb = (uint32_t)__builtin_bit_cast(unsigned short, l);
  return (hb << 16) | lb;
}

// conv1 via MFMA (fp16 2-limb split). Round-8 version verbatim.
__global__ __launch_bounds__(256) void conv1_mfma_k(const float* __restrict__ x,
                                                    const float* __restrict__ w1,
                                                    const float* __restrict__ mean,
                                                    uint32_t* __restrict__ b1p) {
  __shared__ uint32_t ximg[4][1032];
  int tid = threadIdx.x;
  int wave = tid >> 6, lane = tid & 63;
  int n = blockIdx.x * 4 + wave;
  uint32_t* xs = ximg[wave];

  const float4* xin = (const float4*)(x + (size_t)n * 1024);
#pragma unroll
  for (int i = 0; i < 4; ++i) {
    float4 v = xin[i * 64 + lane];
    float fv[4] = {v.x, v.y, v.z, v.w};
#pragma unroll
    for (int e = 0; e < 4; ++e)
      xs[4 * (i * 64 + lane) + e] = pack_f16_pair(fv[e]);
  }

  int bc = lane & 31;
  int khsel = lane >> 5;
  f16x8 Bh[2], Bl[2];
#pragma unroll
  for (int kh = 0; kh < 2; ++kh)
#pragma unroll
    for (int j = 0; j < 8; ++j) {
      int t = kh * 16 + khsel * 8 + j;
      float wv = (bc < 20 && t < 25) ? w1[bc * 25 + t] : 0.f;
      uint32_t pp = pack_f16_pair(wv);
      Bh[kh][j] = __builtin_bit_cast(_Float16, (unsigned short)(pp >> 16));
      Bl[kh][j] = __builtin_bit_cast(_Float16, (unsigned short)(pp & 0xffffu));
    }
  float mv = (bc < 20) ? mean[bc] : 3.0e38f;

  int offs[2][8];
#pragma unroll
  for (int kh = 0; kh < 2; ++kh)
#pragma unroll
    for (int j = 0; j < 8; ++j) {
      int t = kh * 16 + khsel * 8 + j;
      if (t > 24) t = 24;
      offs[kh][j] = (t / 5) * 32 + (t % 5);
    }

  int m = lane & 31;
  const float INV = 1.0f / 4096.0f;

  for (int pp = 0; pp < 14; ++pp) {
    unsigned long long bacc[16];
#pragma unroll
    for (int r = 0; r < 16; ++r) bacc[r] = 0ull;
#pragma unroll
    for (int py2 = 0; py2 < 2; ++py2) {
      int py = 2 * pp + py2;
      int base = py * 32 + m;
      f16x8 Ah[2], Al[2];
#pragma unroll
      for (int kh = 0; kh < 2; ++kh)
#pragma unroll
        for (int j = 0; j < 8; ++j) {
          uint32_t v = xs[base + offs[kh][j]];
          Ah[kh][j] = __builtin_bit_cast(_Float16, (unsigned short)(v >> 16));
          Al[kh][j] = __builtin_bit_cast(_Float16, (unsigned short)(v & 0xffffu));
        }
      f32x16 acc0, acc1;
#pragma unroll
      for (int i = 0; i < 16; ++i) { acc0[i] = 0.f; acc1[i] = 0.f; }
      acc0 = __builtin_amdgcn_mfma_f32_32x32x16_f16(Ah[0], Bh[0], acc0, 0, 0, 0);
      acc0 = __builtin_amdgcn_mfma_f32_32x32x16_f16(Ah[1], Bh[1], acc0, 0, 0, 0);
      acc1 = __builtin_amdgcn_mfma_f32_32x32x16_f16(Ah[0], Bl[0], acc1, 0, 0, 0);
      acc1 = __builtin_amdgcn_mfma_f32_32x32x16_f16(Ah[1], Bl[1], acc1, 0, 0, 0);
      acc1 = __builtin_amdgcn_mfma_f32_32x32x16_f16(Al[0], Bh[0], acc1, 0, 0, 0);
      acc1 = __builtin_amdgcn_mfma_f32_32x32x16_f16(Al[1], Bh[1], acc1, 0, 0, 0);
#pragma unroll
      for (int r = 0; r < 16; ++r)
        bacc[r] |= __ballot((acc0[r] + INV * acc1[r]) > mv);
    }
    uint32_t pm = 0;
#pragma unroll
    for (int pc = 0; pc < 14; ++pc) {
      int px0 = 2 * pc;
      int r0 = (px0 & 3) + 4 * (px0 >> 3);
      int h0 = (px0 >> 2) & 1;
      unsigned long long mm = bacc[r0] | bacc[r0 + 1];
      uint32_t val = (uint32_t)(mm >> (32 * h0));
      if (lane == pc) pm = val;
    }
    if (lane < 14) b1p[(size_t)n * 196 + pp * 14 + lane] = pm;
  }
}

// Fused conv2+pool/sign+linear+fc. Round-10 version verbatim.
__global__ __launch_bounds__(512) void conv2lin_k(const uint32_t* __restrict__ b1p,
                                                  const uint32_t* __restrict__ wp2,
                                                  const unsigned long long* __restrict__ lwp,
                                                  const float* __restrict__ alpha,
                                                  const float* __restrict__ fcw,
                                                  const float* __restrict__ fcb,
                                                  float* __restrict__ out) {
  __shared__ uint32_t wsh[1250];
  __shared__ uint32_t bm[8][196];
  __shared__ int sumpc[8][100];
  __shared__ char uni[8][2048];
  int tid = threadIdx.x;
  int wave = tid >> 6, lane = tid & 63;
  int n = blockIdx.x * 8 + wave;
  signed char* s2w = (signed char*)uni[wave];
  float* hshw = (float*)uni[wave];

  for (int i = tid; i < 1250; i += 512) wsh[i] = wp2[i];
#pragma unroll
  for (int rd = 0; rd < 4; ++rd) {
    int idx = rd * 64 + lane;
    if (idx < 196) bm[wave][idx] = b1p[(size_t)n * 196 + idx];
  }
  __syncthreads();

#pragma unroll
  for (int rd = 0; rd < 2; ++rd) {
    int pp = rd * 64 + lane;
    if (pp < 100) {
      int Y = pp / 10, X = pp % 10, s = 0;
#pragma unroll
      for (int ky = 0; ky < 5; ++ky)
#pragma unroll
        for (int kx = 0; kx < 5; ++kx)
          s += __popc(bm[wave][(Y + ky) * 14 + X + kx]);
      sumpc[wave][pp] = s;
    }
  }

#pragma unroll
  for (int rd = 0; rd < 4; ++rd) {
    int unit = rd * 64 + lane;
    if (unit < 250) {
      int oc = unit / 5, r = unit % 5;
      uint32_t w[25];
#pragma unroll
      for (int i = 0; i < 25; ++i) w[i] = wsh[oc * 25 + i];
      for (int pc = 0; pc < 5; ++pc) {
        uint32_t pa[6][6];
#pragma unroll
        for (int rr = 0; rr < 6; ++rr)
#pragma unroll
          for (int cc = 0; cc < 6; ++cc)
            pa[rr][cc] = bm[wave][(2 * r + rr) * 14 + 2 * pc + cc];
        int best = -1000000;
#pragma unroll
        for (int dy = 0; dy < 2; ++dy)
#pragma unroll
          for (int dx = 0; dx < 2; ++dx) {
            int a = 0;
#pragma unroll
            for (int ky = 0; ky < 5; ++ky)
#pragma unroll
              for (int kx = 0; kx < 5; ++kx)
                a += __popc(w[ky * 5 + kx] & pa[dy + ky][dx + kx]);
            a = 2 * a - sumpc[wave][(2 * r + dy) * 10 + 2 * pc + dx];
            if (a > best) best = a;
          }
        s2w[5 * unit + pc] = (signed char)((best > 0) - (best < 0));
      }
    }
  }
  if (lane < 30) s2w[1250 + lane] = 0;

  unsigned long long Pm[20], Nm[20];
  int cp = 0, cn = 0;
#pragma unroll
  for (int k = 0; k < 20; ++k) {
    signed char v = s2w[k * 64 + lane];
    unsigned long long P = __ballot(v > 0);
    unsigned long long N = __ballot(v < 0);
    Pm[k] = P; Nm[k] = N;
    cp += __popcll(P); cn += __popcll(N);
  }

#pragma unroll
  for (int rd = 0; rd < 8; ++rd) {
    int j = rd * 64 + lane;
    float y = 0.f;
    if (j < 500) {
      const ulonglong2* W2 = (const ulonglong2*)(lwp + (size_t)j * 20);
      int a = 0, b = 0;
#pragma unroll
      for (int i = 0; i < 10; ++i) {
        ulonglong2 w2v = W2[i];
        a += __popcll(w2v.x & Pm[2 * i]) + __popcll(w2v.y & Pm[2 * i + 1]);
        b += __popcll(w2v.x & Nm[2 * i]) + __popcll(w2v.y & Nm[2 * i + 1]);
      }
      int dot = 2 * (a - b) - cp + cn;
      y = alpha[j] * (float)dot;
      y = fminf(1.0f, fmaxf(-1.0f, y));
    }
    hshw[rd * 64 + lane] = y;
  }

  float hv[8];
#pragma unroll
  for (int k = 0; k < 8; ++k) hv[k] = hshw[k * 64 + lane];
#pragma unroll
  for (int o = 0; o < 10; ++o) {
    float pa = 0.f;
#pragma unroll
    for (int k = 0; k < 8; ++k) {
      int j = k * 64 + lane;
      if (j < 500) pa += hv[k] * fcw[o * 500 + j];
    }
    for (int off = 32; off > 0; off >>= 1) pa += __shfl_down(pa, off, 64);
    if (lane == 0) out[(size_t)n * 10 + o] = pa + fcb[o];
  }
}

extern "C" void kernel_launch(void* const* d_in, const int* in_sizes, int n_in,
                              void* d_out, int out_size, void* d_ws, size_t ws_size,
                              hipStream_t stream) {
  const float* x   = (const float*)d_in[0];
  const float* w1  = (const float*)d_in[1];
  const float* w2  = (const float*)d_in[2];
  const float* lw  = (const float*)d_in[3];
  const float* fcw = (const float*)d_in[4];
  const float* fcb = (const float*)d_in[5];
  float* out = (float*)d_out;
  char* ws = (char*)d_ws;

  float*    mean  = (float*)(ws + 0);
  uint32_t* wp2   = (uint32_t*)(ws + 128);
  float*    alpha = (float*)(ws + 5632);
  unsigned long long* lwp = (unsigned long long*)(ws + 7680);
  float*    partial = (float*)(ws + 87808);
  uint32_t* b1p   = (uint32_t*)(ws + 1136384);
  float*    partial2 = (float*)(ws + 7558912);

  prepsum_k<<<386, 256, 0, stream>>>(lw, w2, x, lwp, alpha, wp2, partial);
  reduce_k<<<32, 256, 0, stream>>>(partial, partial2);
  mean_k<<<1, 256, 0, stream>>>(partial2, w1, mean);
  conv1_mfma_k<<<2048, 256, 0, stream>>>(x, w1, mean, b1p);
  conv2lin_k<<<1024, 512, 0, stream>>>(b1p, wp2, lwp, alpha, fcw, fcb, out);
}